// Round 14
// baseline (300.196 us; speedup 1.0000x reference)
//
#include <hip/hip_runtime.h>
#include <cmath>

// GPTNeoXRoutedMLP: N=2048 tokens, H=1024, F=4096, E=8, topk=2.
// R14 = R13 with gemm2's B-register pipeline deepened to a 2-iteration lead:
// 4 named f32x4[4] reg sets, unroll-by-4 main loop, 4-iter peeled tail with
// exact counted vmcnt (steady 12/10 -> tail 8/6 -> 2/0). Everything else
// (prep/scatter/gemm1/combine, all R13-verified) is byte-identical.

#define H_DIM 1024
#define F_DIM 4096
#define E_NUM 8
#define N_TOK 2048
#define BK 32
#define MAX_SLOTS 5120
#define MAX_MT 40                  // 128-row tiles
#define G1_GRID (MAX_MT * 32)      // 1280
#define G2_GRID (MAX_MT * 8 * 2)   // 640 (8 nt x 2 ks)
#define XCHUNKS (N_TOK * H_DIM / 8)

typedef short s16x4 __attribute__((ext_vector_type(4)));
typedef short s16x8 __attribute__((ext_vector_type(8)));
typedef float f32x4 __attribute__((ext_vector_type(4)));
typedef __attribute__((address_space(3))) const unsigned short* lds_us;

__device__ __forceinline__ unsigned short f2bf(float f) {
  unsigned int u = __float_as_uint(f);
  u += 0x7fffu + ((u >> 16) & 1u);   // RNE
  return (unsigned short)(u >> 16);
}

__device__ __forceinline__ void gload_lds16(const void* g, void* l) {
  __builtin_amdgcn_global_load_lds(
      (const __attribute__((address_space(1))) unsigned int*)g,
      (__attribute__((address_space(3))) unsigned int*)l, 16, 0, 0);
}

__device__ __forceinline__ float fast_gelu(float v) {
  const float w = v * (1.0f + 0.044715f * v * v);
  const float t = __expf(-1.5957691216f * w);
  return v / (1.0f + t);
}

__device__ __forceinline__ unsigned int pk_bf16(float lo, float hi) {
  unsigned int r;
  asm("v_cvt_pk_bf16_f32 %0, %1, %2" : "=v"(r) : "v"(lo), "v"(hi));
  return r;
}

template<int OFS>
__device__ __forceinline__ s16x4 trread(lds_us p) {
  s16x4 r;
  asm volatile("ds_read_b64_tr_b16 %0, %1 offset:%2" : "=v"(r) : "v"(p), "i"(OFS));
  return r;
}

// regions at 1040B stride (1024B data + 16B skew) — R10/R13-verified read map
__device__ __forceinline__ void ld_b4(lds_us bp, s16x8 bb[4]) {
  s16x4 p0 = trread<0>(bp),    q0 = trread<512>(bp);
  s16x4 p1 = trread<1040>(bp), q1 = trread<1552>(bp);
  s16x4 p2 = trread<2080>(bp), q2 = trread<2592>(bp);
  s16x4 p3 = trread<3120>(bp), q3 = trread<3632>(bp);
  bb[0] = __builtin_shufflevector(p0, q0, 0, 1, 2, 3, 4, 5, 6, 7);
  bb[1] = __builtin_shufflevector(p1, q1, 0, 1, 2, 3, 4, 5, 6, 7);
  bb[2] = __builtin_shufflevector(p2, q2, 0, 1, 2, 3, 4, 5, 6, 7);
  bb[3] = __builtin_shufflevector(p3, q3, 0, 1, 2, 3, 4, 5, 6, 7);
}

// ---------------- prep: x cvt (128 blk) | router (512 blk, no atomics) ----------------
__global__ __launch_bounds__(256) void prep_k(
    const float* __restrict__ x, unsigned short* __restrict__ xb,
    const float* __restrict__ rw, int* __restrict__ topk_e, float* __restrict__ topk_s) {
  const int b = blockIdx.x;
  const int t = threadIdx.x;
  if (b < 128) {
    const int step = 128 * 256;
#pragma unroll 4
    for (int c = b * 256 + t; c < XCHUNKS; c += step) {
      const size_t i = (size_t)c * 8;
      f32x4 a = *(const f32x4*)(x + i);
      f32x4 d = *(const f32x4*)(x + i + 4);
      s16x8 u;
#pragma unroll
      for (int j = 0; j < 4; ++j) { u[j] = (short)f2bf(a[j]); u[4 + j] = (short)f2bf(d[j]); }
      *(s16x8*)&xb[i] = u;
    }
    return;
  }
  const int n = (b - 128) * 4 + (t >> 6);
  const int l = t & 63;
  float part[E_NUM];
#pragma unroll
  for (int e = 0; e < E_NUM; ++e) part[e] = 0.f;
  const float* xr = x + (size_t)n * H_DIM;
  for (int h = l; h < H_DIM; h += 64) {
    const float xv = xr[h];
    const float* rwr = rw + h * E_NUM;
#pragma unroll
    for (int e = 0; e < E_NUM; ++e) part[e] += xv * rwr[e];
  }
#pragma unroll
  for (int e = 0; e < E_NUM; ++e) {
#pragma unroll
    for (int off = 32; off > 0; off >>= 1) part[e] += __shfl_down(part[e], off);
  }
  if (l == 0) {
    float v0 = -3.4e38f, v1 = -3.4e38f;
    int i0 = 0, i1 = 0;
#pragma unroll
    for (int e = 0; e < E_NUM; ++e) {
      float v = part[e];
      if (v > v0) { v1 = v0; i1 = i0; v0 = v; i0 = e; }   // strict >: lowest index wins
      else if (v > v1) { v1 = v; i1 = e; }
    }
    const float e1 = expf(v1 - v0);
    const float inv = 1.f / (1.f + e1);
    topk_e[2 * n] = i0; topk_e[2 * n + 1] = i1;
    topk_s[2 * n] = inv; topk_s[2 * n + 1] = e1 * inv;
  }
}

// ------- Scatter: histogram, 128-padded offsets, slot lists + token->slot map -------
__global__ __launch_bounds__(256) void scatter_k(
    int* __restrict__ meta, const int* __restrict__ topk_e,
    int* __restrict__ slot_token, int* __restrict__ token_slots) {
  __shared__ int cnt[4][8];
  __shared__ int soff[9];
  __shared__ int scur[8];
  const int t = threadIdx.x;
  const int wv = t >> 6;
  if (t < 32) cnt[t >> 3][t & 7] = 0;
  if (t < 8) scur[t] = 0;
  __syncthreads();
  for (int a = t; a < N_TOK * 2; a += 256)
    atomicAdd(&cnt[wv][topk_e[a]], 1);
  __syncthreads();
  if (t == 0) {
    int acc = 0;
    for (int e = 0; e < E_NUM; ++e) {
      const int c = cnt[0][e] + cnt[1][e] + cnt[2][e] + cnt[3][e];
      soff[e] = acc;
      meta[8 + e] = acc;
      acc += ((c + 127) / 128) * 128;
    }
    soff[8] = acc;
    meta[16] = acc;
  }
  __syncthreads();
  for (int a = t; a < N_TOK * 2; a += 256) {
    const int e = topk_e[a];
    const int pos = atomicAdd(&scur[e], 1);
    const int slot = soff[e] + pos;
    slot_token[slot] = a >> 1;
    token_slots[a] = slot;
  }
}

// ====== GEMM1: h = gelu(xb[gather] @ w1[e](f32) + b1), 128x128x32 direct-f32 ======
// (byte-identical to R13)
__global__ __launch_bounds__(256, 3) void gemm1_f(
    const unsigned short* __restrict__ xb, const float* __restrict__ w1,
    const float* __restrict__ b1, const int* __restrict__ meta,
    const int* __restrict__ slot_token, unsigned short* __restrict__ hbuf) {
  __shared__ __align__(16) unsigned short Al[3 * 4096];
  __shared__ __align__(16) char Bl[2 * 8 * 1040];
  const int total = meta[16];
  const int c = blockIdx.x & 7;
  const int j = blockIdx.x >> 3;
  const int mt = j >> 2, nt = c * 4 + (j & 3);
  const int m0 = mt * 128;
  if (m0 >= total) return;
  int exp = 0;
#pragma unroll
  for (int e = 1; e < E_NUM; ++e) if (m0 >= meta[8 + e]) exp = e;
  const int n0 = nt * 128;
  const int t = threadIdx.x, w = t >> 6, l = t & 63;
  const int wm = w >> 1, wn = w & 1, lr = l & 15, lg = l >> 4;

  const unsigned short* pA[2];
#pragma unroll
  for (int i = 0; i < 2; ++i) {
    const int q = w * 2 + i;
    const int row = q * 16 + (l >> 2);
    int tk = slot_token[m0 + row]; if (tk < 0) tk = 0;
    pA[i] = xb + (size_t)tk * H_DIM + (((l & 3) ^ ((l >> 3) & 3)) << 3);
  }
  const int krow = t >> 3, cg = t & 7;
  const float* pB = w1 + (size_t)exp * H_DIM * F_DIM + (size_t)krow * F_DIM + n0 + cg * 16;
  const int wb = cg * 1040 + ((krow >> 2) & 1) * 512 + (krow >> 3) * 128 + (krow & 3) * 32;

  const f32x4 fzero = {0.f, 0.f, 0.f, 0.f};
  f32x4 acc[4][4];
#pragma unroll
  for (int a = 0; a < 4; ++a)
#pragma unroll
    for (int b = 0; b < 4; ++b) acc[a][b] = fzero;
  const int fofs = ((lg ^ ((lr >> 1) & 3)) << 3);

#define ISSUEA1(Ad)                                                         \
  _Pragma("unroll") for (int i = 0; i < 2; ++i) {                           \
    gload_lds16(pA[i], (Ad) + (w * 2 + i) * 512); pA[i] += BK;              \
  }
#define LOADB1(v)                                                           \
  { _Pragma("unroll") for (int q_ = 0; q_ < 4; ++q_) v[q_] = *(const f32x4*)(pB + q_ * 4); \
    pB += (size_t)BK * F_DIM; }
#define CVTB1(v, Bd)                                                        \
  { int4 u0, u1;                                                            \
    u0.x = (int)pk_bf16(v[0][0], v[0][1]); u0.y = (int)pk_bf16(v[0][2], v[0][3]); \
    u0.z = (int)pk_bf16(v[1][0], v[1][1]); u0.w = (int)pk_bf16(v[1][2], v[1][3]); \
    u1.x = (int)pk_bf16(v[2][0], v[2][1]); u1.y = (int)pk_bf16(v[2][2], v[2][3]); \
    u1.z = (int)pk_bf16(v[3][0], v[3][1]); u1.w = (int)pk_bf16(v[3][2], v[3][3]); \
    *(int4*)((Bd) + wb) = u0; *(int4*)((Bd) + wb + 16) = u1; }
#define MFMA1(Ac, Bc)                                                       \
  { lds_us bp = (lds_us)((Bc) + wn * 4160) + l * 4;                         \
    s16x8 af[4], bb[4];                                                     \
    _Pragma("unroll") for (int fm = 0; fm < 4; ++fm)                        \
      af[fm] = *(const s16x8*)&(Ac)[(wm * 64 + fm * 16 + lr) * 32 + fofs];  \
    ld_b4(bp, bb);                                                          \
    asm volatile("s_waitcnt lgkmcnt(0)" ::: "memory");                      \
    __builtin_amdgcn_sched_barrier(0);                                      \
    _Pragma("unroll") for (int fm = 0; fm < 4; ++fm)                        \
      _Pragma("unroll") for (int fn = 0; fn < 4; ++fn)                      \
        acc[fm][fn] = __builtin_amdgcn_mfma_f32_16x16x32_bf16(af[fm], bb[fn], acc[fm][fn], 0, 0, 0); \
  }

  unsigned short *a0 = Al, *a1 = Al + 4096, *a2 = Al + 8192;
  char *bl0 = Bl, *bl1 = Bl + 8320;
  f32x4 vP[4], vQ[4];
  const int NT = H_DIM / BK;  // 32
  LOADB1(vP) ISSUEA1(a0)
  LOADB1(vQ) ISSUEA1(a1)
  asm volatile("s_waitcnt vmcnt(6)" ::: "memory");
  CVTB1(vP, bl0)
  asm volatile("s_waitcnt lgkmcnt(0)" ::: "memory");
  __builtin_amdgcn_s_barrier();
  for (int it = 0; it < NT / 2; ++it) {
    const bool has2 = it < NT / 2 - 1;
    if (has2) { ISSUEA1(a2) LOADB1(vP) }
    if (has2) asm volatile("s_waitcnt vmcnt(6)" ::: "memory");
    else      asm volatile("s_waitcnt vmcnt(0)" ::: "memory");
    CVTB1(vQ, bl1)
    MFMA1(a0, bl0)
    asm volatile("s_waitcnt lgkmcnt(0)" ::: "memory");
    __builtin_amdgcn_s_barrier();
    { unsigned short* tmp = a0; a0 = a1; a1 = a2; a2 = tmp; }
    if (has2) { ISSUEA1(a2) LOADB1(vQ) }
    if (has2) asm volatile("s_waitcnt vmcnt(6)" ::: "memory");
    else      asm volatile("s_waitcnt vmcnt(0)" ::: "memory");
    if (has2) { CVTB1(vP, bl0) }
    MFMA1(a0, bl1)
    if (has2) {
      asm volatile("s_waitcnt lgkmcnt(0)" ::: "memory");
      __builtin_amdgcn_s_barrier();
    }
    { unsigned short* tmp = a0; a0 = a1; a1 = a2; a2 = tmp; }
  }

#pragma unroll
  for (int fn = 0; fn < 4; ++fn) {
    const int col = n0 + wn * 64 + fn * 16 + lr;
    const float bias = b1[exp * F_DIM + col];
#pragma unroll
    for (int fm = 0; fm < 4; ++fm) {
      const int rbase = m0 + wm * 64 + fm * 16 + lg * 4;
#pragma unroll
      for (int i = 0; i < 4; ++i) {
        hbuf[(size_t)(rbase + i) * F_DIM + col] = f2bf(fast_gelu(acc[fm][fn][i] + bias));
      }
    }
  }
}

// ====== GEMM2: y[ks][slot] = hbuf @ w2[e](f32), 128x128x32 splitK=2 ======
// Deep pipeline: B-regs 2-iteration lead (4 sets), A gload ring-3 (2-it lead).
__global__ __launch_bounds__(256, 3) void gemm2_f(
    const unsigned short* __restrict__ hbuf, const float* __restrict__ w2,
    const int* __restrict__ meta, unsigned short* __restrict__ yb) {
  __shared__ __align__(16) unsigned short Al[3 * 4096];
  __shared__ __align__(16) char Bl[2 * 8 * 1040];
  const int total = meta[16];
  const int c = blockIdx.x & 7;
  const int r = blockIdx.x >> 3;
  const int nt = c;
  const int ks = r & 1;
  const int mt = r >> 1;
  const int m0 = mt * 128;
  if (m0 >= total) return;
  int exp = 0;
#pragma unroll
  for (int e = 1; e < E_NUM; ++e) if (m0 >= meta[8 + e]) exp = e;
  const int n0 = nt * 128;
  const int k0 = ks * 2048;
  const int t = threadIdx.x, w = t >> 6, l = t & 63;
  const int wm = w >> 1, wn = w & 1, lr = l & 15, lg = l >> 4;

  const unsigned short* pA[2];
#pragma unroll
  for (int i = 0; i < 2; ++i) {
    const int q = w * 2 + i;
    const int row = q * 16 + (l >> 2);
    pA[i] = hbuf + (size_t)(m0 + row) * F_DIM + k0 + (((l & 3) ^ ((l >> 3) & 3)) << 3);
  }
  const int krow = t >> 3, cg = t & 7;
  const float* pB = w2 + (size_t)exp * F_DIM * H_DIM + (size_t)(k0 + krow) * H_DIM + n0 + cg * 16;
  const int wb = cg * 1040 + ((krow >> 2) & 1) * 512 + (krow >> 3) * 128 + (krow & 3) * 32;

  const f32x4 fzero = {0.f, 0.f, 0.f, 0.f};
  f32x4 acc[4][4];
#pragma unroll
  for (int a = 0; a < 4; ++a)
#pragma unroll
    for (int b = 0; b < 4; ++b) acc[a][b] = fzero;
  const int fofs = ((lg ^ ((lr >> 1) & 3)) << 3);

#define ISSUEA2(Ad)                                                         \
  _Pragma("unroll") for (int i = 0; i < 2; ++i) {                           \
    gload_lds16(pA[i], (Ad) + (w * 2 + i) * 512); pA[i] += BK;              \
  }
#define LOADB2(v)                                                           \
  { _Pragma("unroll") for (int q_ = 0; q_ < 4; ++q_) v[q_] = *(const f32x4*)(pB + q_ * 4); \
    pB += (size_t)BK * H_DIM; }

  unsigned short *a0 = Al, *a1 = Al + 4096, *a2 = Al + 8192;
  char *bl0 = Bl, *bl1 = Bl + 8320;
  f32x4 v0[4], v1[4], v2[4], v3[4];
  const int NT = 2048 / BK;  // 64

  // prologue: A0,A1 to LDS; B0,B1,B2 to regs (2-iter lead established)
  ISSUEA2(a0) LOADB2(v0)
  ISSUEA2(a1) LOADB2(v1)
  LOADB2(v2)
  asm volatile("s_waitcnt vmcnt(10)" ::: "memory");   // A0 + B0 retired
  CVTB1(v0, bl0)
  asm volatile("s_waitcnt lgkmcnt(0)" ::: "memory");
  __builtin_amdgcn_s_barrier();

  // steady body at unroll position P (i%4==P): load B(i+3)->v[(P+3)&3],
  // CVT v[(P+1)&3] -> bl[(P+1)&1], MFMA(a0, bl[P&1]).
#define STEP2(VL, VC, BLW, BLR)                                             \
  {                                                                         \
    ISSUEA2(a2) LOADB2(VL)                                                  \
    asm volatile("s_waitcnt vmcnt(12)" ::: "memory");                       \
    CVTB1(VC, BLW)                                                          \
    MFMA1(a0, BLR)                                                          \
    asm volatile("s_waitcnt vmcnt(10) lgkmcnt(0)" ::: "memory");            \
    __builtin_amdgcn_s_barrier();                                           \
    { unsigned short* tmp = a0; a0 = a1; a1 = a2; a2 = tmp; }               \
  }

  for (int it = 0; it < (NT - 4) / 4; ++it) {   // i = 0..NT-5
    STEP2(v3, v1, bl1, bl0)   // i%4==0
    STEP2(v0, v2, bl0, bl1)   // i%4==1
    STEP2(v1, v3, bl1, bl0)   // i%4==2
    STEP2(v2, v0, bl0, bl1)   // i%4==3
  }
  // peeled tail: i = NT-4 (%4==0, steady), NT-3, NT-2, NT-1
  STEP2(v3, v1, bl1, bl0)                       // i = NT-4
  {                                             // i = NT-3: A(NT-1) only
    ISSUEA2(a2)
    asm volatile("s_waitcnt vmcnt(8)" ::: "memory");
    CVTB1(v2, bl0)
    MFMA1(a0, bl1)
    asm volatile("s_waitcnt vmcnt(6) lgkmcnt(0)" ::: "memory");
    __builtin_amdgcn_s_barrier();
    { unsigned short* tmp = a0; a0 = a1; a1 = a2; a2 = tmp; }
  }
  {                                             // i = NT-2: no issues
    asm volatile("s_waitcnt vmcnt(2)" ::: "memory");
    CVTB1(v3, bl1)
    MFMA1(a0, bl0)
    asm volatile("s_waitcnt vmcnt(0) lgkmcnt(0)" ::: "memory");
    __builtin_amdgcn_s_barrier();
    { unsigned short* tmp = a0; a0 = a1; a1 = a2; a2 = tmp; }
  }
  MFMA1(a0, bl1)                                // i = NT-1

  unsigned short* yk = yb + (size_t)ks * MAX_SLOTS * H_DIM;
#pragma unroll
  for (int fn = 0; fn < 4; ++fn) {
    const int col = n0 + wn * 64 + fn * 16 + lr;
#pragma unroll
    for (int fm = 0; fm < 4; ++fm) {
      const int rbase = m0 + wm * 64 + fm * 16 + lg * 4;
#pragma unroll
      for (int i = 0; i < 4; ++i) {
        yk[(size_t)(rbase + i) * H_DIM + col] = f2bf(acc[fm][fn][i]);
      }
    }
  }
}

// ---- combine: out[tok] = s0*(y0[sl0]+y1[sl0]+b2[e0]) + s1*(y0[sl1]+y1[sl1]+b2[e1]) ----
__global__ __launch_bounds__(256) void combine_k(
    const unsigned short* __restrict__ yb, const float* __restrict__ b2,
    const int* __restrict__ token_slots, const int* __restrict__ topk_e,
    const float* __restrict__ topk_s, float* __restrict__ out) {
  const int tok = blockIdx.x;
  const int c4 = threadIdx.x * 4;
  const int sl0 = token_slots[2 * tok], sl1 = token_slots[2 * tok + 1];
  const float s0 = topk_s[2 * tok], s1 = topk_s[2 * tok + 1];
  const int e0 = topk_e[2 * tok], e1 = topk_e[2 * tok + 1];
  const unsigned short* y1p = yb + (size_t)MAX_SLOTS * H_DIM;
  ushort4 a0 = *(const ushort4*)(yb  + (size_t)sl0 * H_DIM + c4);
  ushort4 a1 = *(const ushort4*)(y1p + (size_t)sl0 * H_DIM + c4);
  ushort4 d0 = *(const ushort4*)(yb  + (size_t)sl1 * H_DIM + c4);
  ushort4 d1 = *(const ushort4*)(y1p + (size_t)sl1 * H_DIM + c4);
  f32x4 ba = *(const f32x4*)(b2 + e0 * H_DIM + c4);
  f32x4 bd = *(const f32x4*)(b2 + e1 * H_DIM + c4);
  const unsigned short* ap0 = &a0.x; const unsigned short* ap1 = &a1.x;
  const unsigned short* dp0 = &d0.x; const unsigned short* dp1 = &d1.x;
  f32x4 o;
#pragma unroll
  for (int j = 0; j < 4; ++j) {
    const float ya = __uint_as_float((unsigned)ap0[j] << 16) + __uint_as_float((unsigned)ap1[j] << 16) + ba[j];
    const float yd = __uint_as_float((unsigned)dp0[j] << 16) + __uint_as_float((unsigned)dp1[j] << 16) + bd[j];
    o[j] = s0 * ya + s1 * yd;
  }
  *(f32x4*)(out + (size_t)tok * H_DIM + c4) = o;
}

extern "C" void kernel_launch(void* const* d_in, const int* in_sizes, int n_in,
                              void* d_out, int out_size, void* d_ws, size_t ws_size,
                              hipStream_t stream) {
  const float* x  = (const float*)d_in[0];
  const float* rw = (const float*)d_in[1];
  const float* w1 = (const float*)d_in[2];
  const float* b1 = (const float*)d_in[3];
  const float* w2 = (const float*)d_in[4];
  const float* b2 = (const float*)d_in[5];
  float* out = (float*)d_out;
  char* ws = (char*)d_ws;

  int*   meta        = (int*)ws;
  int*   topk_e      = (int*)(ws + 4096);
  float* topk_s      = (float*)(ws + 36864);
  int*   slot_token  = (int*)(ws + 69632);
  int*   token_slots = (int*)(ws + 102400);
  unsigned short* xb   = (unsigned short*)(ws + (1ull << 20));
  unsigned short* hbuf = (unsigned short*)(ws + (6ull << 20));    // 40 MB, ends 46
  unsigned short* yb   = (unsigned short*)(ws + (46ull << 20));   // 20 MB, ends 66

  hipMemsetAsync(meta, 0, 256, stream);
  hipMemsetAsync(slot_token, 0xFF, MAX_SLOTS * sizeof(int), stream);

  prep_k<<<128 + 512, 256, 0, stream>>>(x, xb, rw, topk_e, topk_s);
  scatter_k<<<1, 256, 0, stream>>>(meta, topk_e, slot_token, token_slots);
  gemm1_f<<<G1_GRID, 256, 0, stream>>>(xb, w1, b1, meta, slot_token, hbuf);
  gemm2_f<<<G2_GRID, 256, 0, stream>>>(hbuf, w2, meta, yb);
  combine_k<<<N_TOK, 256, 0, stream>>>(yb, b2, token_slots, topk_e, topk_s, out);
}

// Round 15
// 225.586 us; speedup vs baseline: 1.3307x; 1.3307x over previous
//
#include <hip/hip_runtime.h>
#include <cmath>

// GPTNeoXRoutedMLP: N=2048 tokens, H=1024, F=4096, E=8, topk=2.
// R15 = R13 (best, 227.9us) with gemm2 splitK 2->4 (grid 640->1280) to fix
// its occupancy starvation (R13: occ 20%, 2.5 blk/CU). yb holds 4 bf16
// partials; combine sums 4 slices. R14's deep B-pipeline reverted (it spilled:
// WRITE_SIZE 18->198 MB). Everything else byte-identical to R13.

#define H_DIM 1024
#define F_DIM 4096
#define E_NUM 8
#define N_TOK 2048
#define BK 32
#define MAX_SLOTS 5120
#define MAX_MT 40                  // 128-row tiles
#define G1_GRID (MAX_MT * 32)      // 1280
#define KSPLIT 4
#define G2_GRID (MAX_MT * 8 * KSPLIT)   // 1280 (8 nt x 4 ks)
#define XCHUNKS (N_TOK * H_DIM / 8)

typedef short s16x4 __attribute__((ext_vector_type(4)));
typedef short s16x8 __attribute__((ext_vector_type(8)));
typedef float f32x4 __attribute__((ext_vector_type(4)));
typedef __attribute__((address_space(3))) const unsigned short* lds_us;

__device__ __forceinline__ unsigned short f2bf(float f) {
  unsigned int u = __float_as_uint(f);
  u += 0x7fffu + ((u >> 16) & 1u);   // RNE
  return (unsigned short)(u >> 16);
}

__device__ __forceinline__ void gload_lds16(const void* g, void* l) {
  __builtin_amdgcn_global_load_lds(
      (const __attribute__((address_space(1))) unsigned int*)g,
      (__attribute__((address_space(3))) unsigned int*)l, 16, 0, 0);
}

__device__ __forceinline__ float fast_gelu(float v) {
  const float w = v * (1.0f + 0.044715f * v * v);
  const float t = __expf(-1.5957691216f * w);
  return v / (1.0f + t);
}

__device__ __forceinline__ unsigned int pk_bf16(float lo, float hi) {
  unsigned int r;
  asm("v_cvt_pk_bf16_f32 %0, %1, %2" : "=v"(r) : "v"(lo), "v"(hi));
  return r;
}

template<int OFS>
__device__ __forceinline__ s16x4 trread(lds_us p) {
  s16x4 r;
  asm volatile("ds_read_b64_tr_b16 %0, %1 offset:%2" : "=v"(r) : "v"(p), "i"(OFS));
  return r;
}

// regions at 1040B stride (1024B data + 16B skew) — R10/R13-verified read map
__device__ __forceinline__ void ld_b4(lds_us bp, s16x8 bb[4]) {
  s16x4 p0 = trread<0>(bp),    q0 = trread<512>(bp);
  s16x4 p1 = trread<1040>(bp), q1 = trread<1552>(bp);
  s16x4 p2 = trread<2080>(bp), q2 = trread<2592>(bp);
  s16x4 p3 = trread<3120>(bp), q3 = trread<3632>(bp);
  bb[0] = __builtin_shufflevector(p0, q0, 0, 1, 2, 3, 4, 5, 6, 7);
  bb[1] = __builtin_shufflevector(p1, q1, 0, 1, 2, 3, 4, 5, 6, 7);
  bb[2] = __builtin_shufflevector(p2, q2, 0, 1, 2, 3, 4, 5, 6, 7);
  bb[3] = __builtin_shufflevector(p3, q3, 0, 1, 2, 3, 4, 5, 6, 7);
}

// ---------------- prep: x cvt (128 blk) | router (512 blk, no atomics) ----------------
__global__ __launch_bounds__(256) void prep_k(
    const float* __restrict__ x, unsigned short* __restrict__ xb,
    const float* __restrict__ rw, int* __restrict__ topk_e, float* __restrict__ topk_s) {
  const int b = blockIdx.x;
  const int t = threadIdx.x;
  if (b < 128) {
    const int step = 128 * 256;
#pragma unroll 4
    for (int c = b * 256 + t; c < XCHUNKS; c += step) {
      const size_t i = (size_t)c * 8;
      f32x4 a = *(const f32x4*)(x + i);
      f32x4 d = *(const f32x4*)(x + i + 4);
      s16x8 u;
#pragma unroll
      for (int j = 0; j < 4; ++j) { u[j] = (short)f2bf(a[j]); u[4 + j] = (short)f2bf(d[j]); }
      *(s16x8*)&xb[i] = u;
    }
    return;
  }
  const int n = (b - 128) * 4 + (t >> 6);
  const int l = t & 63;
  float part[E_NUM];
#pragma unroll
  for (int e = 0; e < E_NUM; ++e) part[e] = 0.f;
  const float* xr = x + (size_t)n * H_DIM;
  for (int h = l; h < H_DIM; h += 64) {
    const float xv = xr[h];
    const float* rwr = rw + h * E_NUM;
#pragma unroll
    for (int e = 0; e < E_NUM; ++e) part[e] += xv * rwr[e];
  }
#pragma unroll
  for (int e = 0; e < E_NUM; ++e) {
#pragma unroll
    for (int off = 32; off > 0; off >>= 1) part[e] += __shfl_down(part[e], off);
  }
  if (l == 0) {
    float v0 = -3.4e38f, v1 = -3.4e38f;
    int i0 = 0, i1 = 0;
#pragma unroll
    for (int e = 0; e < E_NUM; ++e) {
      float v = part[e];
      if (v > v0) { v1 = v0; i1 = i0; v0 = v; i0 = e; }   // strict >: lowest index wins
      else if (v > v1) { v1 = v; i1 = e; }
    }
    const float e1 = expf(v1 - v0);
    const float inv = 1.f / (1.f + e1);
    topk_e[2 * n] = i0; topk_e[2 * n + 1] = i1;
    topk_s[2 * n] = inv; topk_s[2 * n + 1] = e1 * inv;
  }
}

// ------- Scatter: histogram, 128-padded offsets, slot lists + token->slot map -------
__global__ __launch_bounds__(256) void scatter_k(
    int* __restrict__ meta, const int* __restrict__ topk_e,
    int* __restrict__ slot_token, int* __restrict__ token_slots) {
  __shared__ int cnt[4][8];
  __shared__ int soff[9];
  __shared__ int scur[8];
  const int t = threadIdx.x;
  const int wv = t >> 6;
  if (t < 32) cnt[t >> 3][t & 7] = 0;
  if (t < 8) scur[t] = 0;
  __syncthreads();
  for (int a = t; a < N_TOK * 2; a += 256)
    atomicAdd(&cnt[wv][topk_e[a]], 1);
  __syncthreads();
  if (t == 0) {
    int acc = 0;
    for (int e = 0; e < E_NUM; ++e) {
      const int c = cnt[0][e] + cnt[1][e] + cnt[2][e] + cnt[3][e];
      soff[e] = acc;
      meta[8 + e] = acc;
      acc += ((c + 127) / 128) * 128;
    }
    soff[8] = acc;
    meta[16] = acc;
  }
  __syncthreads();
  for (int a = t; a < N_TOK * 2; a += 256) {
    const int e = topk_e[a];
    const int pos = atomicAdd(&scur[e], 1);
    const int slot = soff[e] + pos;
    slot_token[slot] = a >> 1;
    token_slots[a] = slot;
  }
}

// ====== GEMM1: h = gelu(xb[gather] @ w1[e](f32) + b1), 128x128x32 direct-f32 ======
// (byte-identical to R13)
__global__ __launch_bounds__(256, 3) void gemm1_f(
    const unsigned short* __restrict__ xb, const float* __restrict__ w1,
    const float* __restrict__ b1, const int* __restrict__ meta,
    const int* __restrict__ slot_token, unsigned short* __restrict__ hbuf) {
  __shared__ __align__(16) unsigned short Al[3 * 4096];
  __shared__ __align__(16) char Bl[2 * 8 * 1040];
  const int total = meta[16];
  const int c = blockIdx.x & 7;
  const int j = blockIdx.x >> 3;
  const int mt = j >> 2, nt = c * 4 + (j & 3);
  const int m0 = mt * 128;
  if (m0 >= total) return;
  int exp = 0;
#pragma unroll
  for (int e = 1; e < E_NUM; ++e) if (m0 >= meta[8 + e]) exp = e;
  const int n0 = nt * 128;
  const int t = threadIdx.x, w = t >> 6, l = t & 63;
  const int wm = w >> 1, wn = w & 1, lr = l & 15, lg = l >> 4;

  const unsigned short* pA[2];
#pragma unroll
  for (int i = 0; i < 2; ++i) {
    const int q = w * 2 + i;
    const int row = q * 16 + (l >> 2);
    int tk = slot_token[m0 + row]; if (tk < 0) tk = 0;
    pA[i] = xb + (size_t)tk * H_DIM + (((l & 3) ^ ((l >> 3) & 3)) << 3);
  }
  const int krow = t >> 3, cg = t & 7;
  const float* pB = w1 + (size_t)exp * H_DIM * F_DIM + (size_t)krow * F_DIM + n0 + cg * 16;
  const int wb = cg * 1040 + ((krow >> 2) & 1) * 512 + (krow >> 3) * 128 + (krow & 3) * 32;

  const f32x4 fzero = {0.f, 0.f, 0.f, 0.f};
  f32x4 acc[4][4];
#pragma unroll
  for (int a = 0; a < 4; ++a)
#pragma unroll
    for (int b = 0; b < 4; ++b) acc[a][b] = fzero;
  const int fofs = ((lg ^ ((lr >> 1) & 3)) << 3);

#define ISSUEA1(Ad)                                                         \
  _Pragma("unroll") for (int i = 0; i < 2; ++i) {                           \
    gload_lds16(pA[i], (Ad) + (w * 2 + i) * 512); pA[i] += BK;              \
  }
#define LOADB1(v)                                                           \
  { _Pragma("unroll") for (int q_ = 0; q_ < 4; ++q_) v[q_] = *(const f32x4*)(pB + q_ * 4); \
    pB += (size_t)BK * F_DIM; }
#define CVTB1(v, Bd)                                                        \
  { int4 u0, u1;                                                            \
    u0.x = (int)pk_bf16(v[0][0], v[0][1]); u0.y = (int)pk_bf16(v[0][2], v[0][3]); \
    u0.z = (int)pk_bf16(v[1][0], v[1][1]); u0.w = (int)pk_bf16(v[1][2], v[1][3]); \
    u1.x = (int)pk_bf16(v[2][0], v[2][1]); u1.y = (int)pk_bf16(v[2][2], v[2][3]); \
    u1.z = (int)pk_bf16(v[3][0], v[3][1]); u1.w = (int)pk_bf16(v[3][2], v[3][3]); \
    *(int4*)((Bd) + wb) = u0; *(int4*)((Bd) + wb + 16) = u1; }
#define MFMA1(Ac, Bc)                                                       \
  { lds_us bp = (lds_us)((Bc) + wn * 4160) + l * 4;                         \
    s16x8 af[4], bb[4];                                                     \
    _Pragma("unroll") for (int fm = 0; fm < 4; ++fm)                        \
      af[fm] = *(const s16x8*)&(Ac)[(wm * 64 + fm * 16 + lr) * 32 + fofs];  \
    ld_b4(bp, bb);                                                          \
    asm volatile("s_waitcnt lgkmcnt(0)" ::: "memory");                      \
    __builtin_amdgcn_sched_barrier(0);                                      \
    _Pragma("unroll") for (int fm = 0; fm < 4; ++fm)                        \
      _Pragma("unroll") for (int fn = 0; fn < 4; ++fn)                      \
        acc[fm][fn] = __builtin_amdgcn_mfma_f32_16x16x32_bf16(af[fm], bb[fn], acc[fm][fn], 0, 0, 0); \
  }

  unsigned short *a0 = Al, *a1 = Al + 4096, *a2 = Al + 8192;
  char *bl0 = Bl, *bl1 = Bl + 8320;
  f32x4 vP[4], vQ[4];
  const int NT = H_DIM / BK;  // 32
  LOADB1(vP) ISSUEA1(a0)
  LOADB1(vQ) ISSUEA1(a1)
  asm volatile("s_waitcnt vmcnt(6)" ::: "memory");
  CVTB1(vP, bl0)
  asm volatile("s_waitcnt lgkmcnt(0)" ::: "memory");
  __builtin_amdgcn_s_barrier();
  for (int it = 0; it < NT / 2; ++it) {
    const bool has2 = it < NT / 2 - 1;
    if (has2) { ISSUEA1(a2) LOADB1(vP) }
    if (has2) asm volatile("s_waitcnt vmcnt(6)" ::: "memory");
    else      asm volatile("s_waitcnt vmcnt(0)" ::: "memory");
    CVTB1(vQ, bl1)
    MFMA1(a0, bl0)
    asm volatile("s_waitcnt lgkmcnt(0)" ::: "memory");
    __builtin_amdgcn_s_barrier();
    { unsigned short* tmp = a0; a0 = a1; a1 = a2; a2 = tmp; }
    if (has2) { ISSUEA1(a2) LOADB1(vQ) }
    if (has2) asm volatile("s_waitcnt vmcnt(6)" ::: "memory");
    else      asm volatile("s_waitcnt vmcnt(0)" ::: "memory");
    if (has2) { CVTB1(vP, bl0) }
    MFMA1(a0, bl1)
    if (has2) {
      asm volatile("s_waitcnt lgkmcnt(0)" ::: "memory");
      __builtin_amdgcn_s_barrier();
    }
    { unsigned short* tmp = a0; a0 = a1; a1 = a2; a2 = tmp; }
  }

#pragma unroll
  for (int fn = 0; fn < 4; ++fn) {
    const int col = n0 + wn * 64 + fn * 16 + lr;
    const float bias = b1[exp * F_DIM + col];
#pragma unroll
    for (int fm = 0; fm < 4; ++fm) {
      const int rbase = m0 + wm * 64 + fm * 16 + lg * 4;
#pragma unroll
      for (int i = 0; i < 4; ++i) {
        hbuf[(size_t)(rbase + i) * F_DIM + col] = f2bf(fast_gelu(acc[fm][fn][i] + bias));
      }
    }
  }
}

// ====== GEMM2: y[ks][slot] = hbuf @ w2[e](f32), 128x128x32 splitK=4 direct-f32 ======
__global__ __launch_bounds__(256, 3) void gemm2_f(
    const unsigned short* __restrict__ hbuf, const float* __restrict__ w2,
    const int* __restrict__ meta, unsigned short* __restrict__ yb) {
  __shared__ __align__(16) unsigned short Al[3 * 4096];
  __shared__ __align__(16) char Bl[2 * 8 * 1040];
  const int total = meta[16];
  const int c = blockIdx.x & 7;           // XCD-local n column (B panels L2-resident)
  const int r = blockIdx.x >> 3;          // 0..159
  const int nt = c;
  const int ks = r & (KSPLIT - 1);
  const int mt = r >> 2;
  const int m0 = mt * 128;
  if (m0 >= total) return;
  int exp = 0;
#pragma unroll
  for (int e = 1; e < E_NUM; ++e) if (m0 >= meta[8 + e]) exp = e;
  const int n0 = nt * 128;
  const int k0 = ks * (F_DIM / KSPLIT);   // ks * 1024
  const int t = threadIdx.x, w = t >> 6, l = t & 63;
  const int wm = w >> 1, wn = w & 1, lr = l & 15, lg = l >> 4;

  const unsigned short* pA[2];
#pragma unroll
  for (int i = 0; i < 2; ++i) {
    const int q = w * 2 + i;
    const int row = q * 16 + (l >> 2);
    pA[i] = hbuf + (size_t)(m0 + row) * F_DIM + k0 + (((l & 3) ^ ((l >> 3) & 3)) << 3);
  }
  const int krow = t >> 3, cg = t & 7;
  const float* pB = w2 + (size_t)exp * F_DIM * H_DIM + (size_t)(k0 + krow) * H_DIM + n0 + cg * 16;
  const int wb = cg * 1040 + ((krow >> 2) & 1) * 512 + (krow >> 3) * 128 + (krow & 3) * 32;

  const f32x4 fzero = {0.f, 0.f, 0.f, 0.f};
  f32x4 acc[4][4];
#pragma unroll
  for (int a = 0; a < 4; ++a)
#pragma unroll
    for (int b = 0; b < 4; ++b) acc[a][b] = fzero;
  const int fofs = ((lg ^ ((lr >> 1) & 3)) << 3);

#define ISSUEA2(Ad)                                                         \
  _Pragma("unroll") for (int i = 0; i < 2; ++i) {                           \
    gload_lds16(pA[i], (Ad) + (w * 2 + i) * 512); pA[i] += BK;              \
  }
#define LOADB2(v)                                                           \
  { _Pragma("unroll") for (int q_ = 0; q_ < 4; ++q_) v[q_] = *(const f32x4*)(pB + q_ * 4); \
    pB += (size_t)BK * H_DIM; }

  unsigned short *a0 = Al, *a1 = Al + 4096, *a2 = Al + 8192;
  char *bl0 = Bl, *bl1 = Bl + 8320;
  f32x4 vP[4], vQ[4];
  const int NT = (F_DIM / KSPLIT) / BK;  // 32
  LOADB2(vP) ISSUEA2(a0)
  LOADB2(vQ) ISSUEA2(a1)
  asm volatile("s_waitcnt vmcnt(6)" ::: "memory");
  CVTB1(vP, bl0)
  asm volatile("s_waitcnt lgkmcnt(0)" ::: "memory");
  __builtin_amdgcn_s_barrier();
  for (int it = 0; it < NT / 2; ++it) {
    const bool has2 = it < NT / 2 - 1;
    if (has2) { ISSUEA2(a2) LOADB2(vP) }
    if (has2) asm volatile("s_waitcnt vmcnt(6)" ::: "memory");
    else      asm volatile("s_waitcnt vmcnt(0)" ::: "memory");
    CVTB1(vQ, bl1)
    MFMA1(a0, bl0)
    asm volatile("s_waitcnt lgkmcnt(0)" ::: "memory");
    __builtin_amdgcn_s_barrier();
    { unsigned short* tmp = a0; a0 = a1; a1 = a2; a2 = tmp; }
    if (has2) { ISSUEA2(a2) LOADB2(vQ) }
    if (has2) asm volatile("s_waitcnt vmcnt(6)" ::: "memory");
    else      asm volatile("s_waitcnt vmcnt(0)" ::: "memory");
    if (has2) { CVTB1(vP, bl0) }
    MFMA1(a0, bl1)
    if (has2) {
      asm volatile("s_waitcnt lgkmcnt(0)" ::: "memory");
      __builtin_amdgcn_s_barrier();
    }
    { unsigned short* tmp = a0; a0 = a1; a1 = a2; a2 = tmp; }
  }

  unsigned short* yk = yb + (size_t)ks * MAX_SLOTS * H_DIM;
#pragma unroll
  for (int fn = 0; fn < 4; ++fn) {
    const int col = n0 + wn * 64 + fn * 16 + lr;
#pragma unroll
    for (int fm = 0; fm < 4; ++fm) {
      const int rbase = m0 + wm * 64 + fm * 16 + lg * 4;
#pragma unroll
      for (int i = 0; i < 4; ++i) {
        yk[(size_t)(rbase + i) * H_DIM + col] = f2bf(acc[fm][fn][i]);
      }
    }
  }
}

// ---- combine: out[tok] = sum_k s_k * (sum_p y_p[sl_k] + b2[e_k]) over topk=2, p=0..3 ----
__global__ __launch_bounds__(256) void combine_k(
    const unsigned short* __restrict__ yb, const float* __restrict__ b2,
    const int* __restrict__ token_slots, const int* __restrict__ topk_e,
    const float* __restrict__ topk_s, float* __restrict__ out) {
  const int tok = blockIdx.x;
  const int c4 = threadIdx.x * 4;
  const int sl0 = token_slots[2 * tok], sl1 = token_slots[2 * tok + 1];
  const float s0 = topk_s[2 * tok], s1 = topk_s[2 * tok + 1];
  const int e0 = topk_e[2 * tok], e1 = topk_e[2 * tok + 1];
  f32x4 ya = *(const f32x4*)(b2 + e0 * H_DIM + c4);
  f32x4 yd = *(const f32x4*)(b2 + e1 * H_DIM + c4);
#pragma unroll
  for (int p = 0; p < KSPLIT; ++p) {
    const unsigned short* yp = yb + (size_t)p * MAX_SLOTS * H_DIM;
    ushort4 a = *(const ushort4*)(yp + (size_t)sl0 * H_DIM + c4);
    ushort4 d = *(const ushort4*)(yp + (size_t)sl1 * H_DIM + c4);
    const unsigned short* ap = &a.x;
    const unsigned short* dp = &d.x;
#pragma unroll
    for (int j = 0; j < 4; ++j) {
      ya[j] += __uint_as_float((unsigned)ap[j] << 16);
      yd[j] += __uint_as_float((unsigned)dp[j] << 16);
    }
  }
  f32x4 o;
#pragma unroll
  for (int j = 0; j < 4; ++j) o[j] = s0 * ya[j] + s1 * yd[j];
  *(f32x4*)(out + (size_t)tok * H_DIM + c4) = o;
}

extern "C" void kernel_launch(void* const* d_in, const int* in_sizes, int n_in,
                              void* d_out, int out_size, void* d_ws, size_t ws_size,
                              hipStream_t stream) {
  const float* x  = (const float*)d_in[0];
  const float* rw = (const float*)d_in[1];
  const float* w1 = (const float*)d_in[2];
  const float* b1 = (const float*)d_in[3];
  const float* w2 = (const float*)d_in[4];
  const float* b2 = (const float*)d_in[5];
  float* out = (float*)d_out;
  char* ws = (char*)d_ws;

  int*   meta        = (int*)ws;
  int*   topk_e      = (int*)(ws + 4096);
  float* topk_s      = (float*)(ws + 36864);
  int*   slot_token  = (int*)(ws + 69632);
  int*   token_slots = (int*)(ws + 102400);
  unsigned short* xb   = (unsigned short*)(ws + (1ull << 20));
  unsigned short* hbuf = (unsigned short*)(ws + (6ull << 20));    // 40 MB, ends 46
  unsigned short* yb   = (unsigned short*)(ws + (46ull << 20));   // 40 MB (4 partials), ends 86

  hipMemsetAsync(meta, 0, 256, stream);
  hipMemsetAsync(slot_token, 0xFF, MAX_SLOTS * sizeof(int), stream);

  prep_k<<<128 + 512, 256, 0, stream>>>(x, xb, rw, topk_e, topk_s);
  scatter_k<<<1, 256, 0, stream>>>(meta, topk_e, slot_token, token_slots);
  gemm1_f<<<G1_GRID, 256, 0, stream>>>(xb, w1, b1, meta, slot_token, hbuf);
  gemm2_f<<<G2_GRID, 256, 0, stream>>>(hbuf, w2, meta, yb);
  combine_k<<<N_TOK, 256, 0, stream>>>(yb, b2, token_slots, topk_e, topk_s, out);
}